// Round 2
// baseline (495.074 us; speedup 1.0000x reference)
//
#include <hip/hip_runtime.h>
#include <stdint.h>

// Problem constants
#define T_TOK 4096
#define D_DIM 1024
#define H_DIM 2048
#define E_EXP 8
#define K_TOP 2
#define NTK   (T_TOK * K_TOP)   // 8192 (token, slot) pairs
#define MT1 256                 // gemm1 M-tile
#define MT2 128                 // gemm2 M-tile
#define MAXT1 48                // multiple of 8, >= 8192/256 + 8
#define MAXT2 72                // multiple of 8, >= 8192/128 + 8

typedef short bf16x8 __attribute__((ext_vector_type(8)));
typedef float f32x4  __attribute__((ext_vector_type(4)));

#define MINI(a, b) ((a) < (b) ? (a) : (b))
#define MFMA_BF16 __builtin_amdgcn_mfma_f32_16x16x32_bf16

__device__ __forceinline__ unsigned short f2bf(float f) {
  unsigned u = __float_as_uint(f);
  u += 0x7fffu + ((u >> 16) & 1u);   // round-to-nearest-even
  return (unsigned short)(u >> 16);
}

// async global->LDS, 16B per lane; lds base must be wave-uniform
#define GLDS16(gp, lp)                                                        \
  __builtin_amdgcn_global_load_lds(                                           \
      (const __attribute__((address_space(1))) void*)(gp),                    \
      (__attribute__((address_space(3))) void*)(lp), 16, 0, 0)

// meta layout (ints):
// [0..7] counts, [8..15] offsets, [16..23] scatter cursors, [24] nt1, [25] nt2
// tiles1 (M=256): e [32..79], r0 [80..127], valid [128..175]
// tiles2 (M=128): e [176..247], r0 [248..319], valid [320..391]

__global__ __launch_bounds__(256) void k_route_count(const int* __restrict__ idx,
                                                     int* __restrict__ meta) {
  __shared__ int h[E_EXP];
  int tid = threadIdx.x;
  if (tid < E_EXP) h[tid] = 0;
  __syncthreads();
  int i = blockIdx.x * 256 + tid;          // 32 blocks x 256 = 8192 exactly
  atomicAdd(&h[idx[i] & (E_EXP - 1)], 1);
  __syncthreads();
  if (tid < E_EXP) atomicAdd(&meta[tid], h[tid]);
}

__global__ __launch_bounds__(64) void k_route_plan(int* __restrict__ meta) {
  if (threadIdx.x) return;
  int off = 0, nt1 = 0, nt2 = 0;
  for (int e = 0; e < E_EXP; ++e) {
    int c = meta[e];
    meta[8 + e]  = off;
    meta[16 + e] = off;                     // scatter cursor
    for (int r = 0; r < c; r += MT1) {
      meta[32 + nt1]  = e;
      meta[80 + nt1]  = off + r;
      meta[128 + nt1] = MINI(MT1, c - r);
      ++nt1;
    }
    for (int r = 0; r < c; r += MT2) {
      meta[176 + nt2] = e;
      meta[248 + nt2] = off + r;
      meta[320 + nt2] = MINI(MT2, c - r);
      ++nt2;
    }
    off += c;
  }
  meta[24] = nt1;
  meta[25] = nt2;
}

__global__ __launch_bounds__(256) void k_route_scatter(const int* __restrict__ idx,
                                                       const float* __restrict__ w,
                                                       int* __restrict__ meta,
                                                       int* __restrict__ rows,
                                                       float* __restrict__ wv) {
  __shared__ int h[E_EXP], base[E_EXP];
  int tid = threadIdx.x;
  if (tid < E_EXP) h[tid] = 0;
  __syncthreads();
  int i = blockIdx.x * 256 + tid;
  int e = idx[i] & (E_EXP - 1);
  int r = atomicAdd(&h[e], 1);             // block-local rank
  __syncthreads();
  if (tid < E_EXP) base[tid] = atomicAdd(&meta[16 + tid], h[tid]);
  __syncthreads();
  int p = base[e] + r;
  rows[p] = i >> 1;  // K_TOP = 2
  wv[p]   = w[i];
}

// ---- fused f32->bf16 convert, 8 floats/thread, 16B stores ----
#define NX8   (T_TOK * D_DIM / 8)               // 524288
#define NW18  (E_EXP * 2 * H_DIM * D_DIM / 8)   // 4194304
#define NW28  (E_EXP * D_DIM * H_DIM / 8)       // 2097152
#define NCVT8 (NX8 + NW18 + NW28)               // 6815744

__global__ __launch_bounds__(256) void k_cvt8(const float* __restrict__ x,
                                              const float* __restrict__ W1,
                                              const float* __restrict__ W2,
                                              unsigned short* __restrict__ xb,
                                              unsigned short* __restrict__ W1b,
                                              unsigned short* __restrict__ W2b) {
  long gid = (long)blockIdx.x * 256 + threadIdx.x;
  const float* src;
  unsigned short* dst;
  long i;
  if (gid < NX8) {
    src = x; dst = xb; i = gid;
  } else if (gid < NX8 + NW18) {
    src = W1; dst = W1b; i = gid - NX8;
  } else if (gid < NCVT8) {
    src = W2; dst = W2b; i = gid - (NX8 + NW18);
  } else return;
  float4 a = ((const float4*)src)[2 * i];
  float4 b = ((const float4*)src)[2 * i + 1];
  uint4 o;
  o.x = f2bf(a.x) | ((unsigned)f2bf(a.y) << 16);
  o.y = f2bf(a.z) | ((unsigned)f2bf(a.w) << 16);
  o.z = f2bf(b.x) | ((unsigned)f2bf(b.y) << 16);
  o.w = f2bf(b.z) | ((unsigned)f2bf(b.w) << 16);
  ((uint4*)dst)[i] = o;
}

// ============================================================================
// GEMM1: h = Xg @ W1e^T (u and gate strips), act = f2bf(u * silu(g) * w_row)
// 8-phase-style schedule: K-slab granule (K=32), 4-granule LDS ring (128 KB),
// prefetch 3 granules ahead, per-phase {ds_read || global_load_lds -> barrier
// -> lgkmcnt(0) -> setprio(1) -> 16 MFMA -> setprio(0) -> barrier}, counted
// vmcnt(8) once per granule (tail 8->4->0, never drains mid-loop).
// Tile 256 x (128u + 128g), 8 waves (2M x 4N), wave-tile 128 x (32u+32g).
// LDS granule layout: [256 rows][32 K] bf16, chunk-XOR swizzle c^=((row>>1)&3)
// (rows are 64 B; pairs of rows share a bank span; XOR spreads the 4 chunk
// slots so the 16-row x 4-chunk b128 read covers distinct 16B slots).
// ============================================================================
__global__ __launch_bounds__(512, 2) void k_gemm1(
    const unsigned short* __restrict__ xb,   // [T][1024] bf16
    const unsigned short* __restrict__ W1b,  // [E][4096][1024] bf16
    const int* __restrict__ meta,
    const int* __restrict__ rows,
    const float* __restrict__ wv,
    unsigned short* __restrict__ act) {      // [8192][2048] bf16
  int bid = blockIdx.x;
  int nt = meta[24];
  // XCD-grouped mapping: the 16 y-blocks of one tile land on one XCD
  int xcd = bid & 7, jj = bid >> 3;
  int y   = jj & 15;
  int tb  = ((jj >> 4) << 3) + xcd;
  if (tb >= nt) return;
  int e     = meta[32 + tb];
  int r0    = meta[80 + tb];
  int valid = meta[128 + tb];
  int n0    = y << 7;                        // 128-col strip of u and of g

  __shared__ unsigned short lA[4][8192];     // 4 x 16 KB : 256 rows x 32 K
  __shared__ unsigned short lB[4][8192];     // 4 x 16 KB : 128u+128g x 32 K

  int tid  = threadIdx.x;
  int wave = tid >> 6, lane = tid & 63;
  int wm = wave >> 2, wn = wave & 3;         // 2 x 4 wave grid
  int fr = lane & 15, q = lane >> 4;
  int swz8 = (q ^ ((fr >> 1) & 3)) << 3;     // per-thread swizzled chunk (ushort)

  const unsigned short* w1e = W1b + (size_t)e * (4096 * 1024);

  // staging sources: pre-swizzled so linear GLDS dest gets swizzled layout
  const unsigned short *pA[2], *pB[2];
#pragma unroll
  for (int it = 0; it < 2; ++it) {
    int s = it * 512 + tid;                  // 16B slot 0..1023
    int r = s >> 2;
    int c = (s & 3) ^ ((s >> 3) & 3);        // (r>>1)&3 == (s>>3)&3
    int tok = rows[r0 + MINI(r, valid - 1)];
    pA[it] = xb + (size_t)tok * 1024 + c * 8;
    int wrow = (r < 128) ? (n0 + r) : (1920 + n0 + r);  // u rows | gate rows
    pB[it] = w1e + (size_t)wrow * 1024 + c * 8;
  }

  auto ISSUE_A = [&](int g) {
    int sl = g & 3, ko = g * 32;
#pragma unroll
    for (int it = 0; it < 2; ++it)
      GLDS16(pA[it] + ko, &lA[sl][(it * 512 + wave * 64) * 8]);
  };
  auto ISSUE_B = [&](int g) {
    int sl = g & 3, ko = g * 32;
#pragma unroll
    for (int it = 0; it < 2; ++it)
      GLDS16(pB[it] + ko, &lB[sl][(it * 512 + wave * 64) * 8]);
  };

  f32x4 zero = {0.f, 0.f, 0.f, 0.f};
  f32x4 au[8][2], ag[8][2];
#pragma unroll
  for (int i = 0; i < 8; ++i)
#pragma unroll
    for (int n = 0; n < 2; ++n) { au[i][n] = zero; ag[i][n] = zero; }

  int abase = ((wm << 7) + fr) * 32 + swz8;  // A read base (ushort)
  int ubase = ((wn << 5) + fr) * 32 + swz8;  // B read base (ushort)

  // prologue: granules 0,1,2 in flight
  ISSUE_A(0); ISSUE_B(0);
  ISSUE_A(1); ISSUE_B(1);
  ISSUE_A(2); ISSUE_B(2);
  asm volatile("s_waitcnt vmcnt(8)" ::: "memory");   // granule 0 landed
  __builtin_amdgcn_s_barrier();

  for (int g = 0; g < 32; ++g) {
    int sl = g & 3;
    const unsigned short* A = lA[sl];
    const unsigned short* B = lB[sl];

    // ---------- phase 0: M-half 0, all B-frags ----------
    bf16x8 a0 = *(const bf16x8*)&A[abase + 0 * 512];
    bf16x8 a1 = *(const bf16x8*)&A[abase + 1 * 512];
    bf16x8 a2 = *(const bf16x8*)&A[abase + 2 * 512];
    bf16x8 a3 = *(const bf16x8*)&A[abase + 3 * 512];
    bf16x8 bu0 = *(const bf16x8*)&B[ubase];
    bf16x8 bu1 = *(const bf16x8*)&B[ubase + 512];
    bf16x8 bg0 = *(const bf16x8*)&B[ubase + 4096];
    bf16x8 bg1 = *(const bf16x8*)&B[ubase + 4608];
    if (g < 29) ISSUE_A(g + 3);
    __builtin_amdgcn_sched_barrier(0);
    __builtin_amdgcn_s_barrier();
    asm volatile("s_waitcnt lgkmcnt(0)" ::: "memory");
    __builtin_amdgcn_sched_barrier(0);
    __builtin_amdgcn_s_setprio(1);
    au[0][0] = MFMA_BF16(a0, bu0, au[0][0], 0, 0, 0);
    au[0][1] = MFMA_BF16(a0, bu1, au[0][1], 0, 0, 0);
    ag[0][0] = MFMA_BF16(a0, bg0, ag[0][0], 0, 0, 0);
    ag[0][1] = MFMA_BF16(a0, bg1, ag[0][1], 0, 0, 0);
    au[1][0] = MFMA_BF16(a1, bu0, au[1][0], 0, 0, 0);
    au[1][1] = MFMA_BF16(a1, bu1, au[1][1], 0, 0, 0);
    ag[1][0] = MFMA_BF16(a1, bg0, ag[1][0], 0, 0, 0);
    ag[1][1] = MFMA_BF16(a1, bg1, ag[1][1], 0, 0, 0);
    au[2][0] = MFMA_BF16(a2, bu0, au[2][0], 0, 0, 0);
    au[2][1] = MFMA_BF16(a2, bu1, au[2][1], 0, 0, 0);
    ag[2][0] = MFMA_BF16(a2, bg0, ag[2][0], 0, 0, 0);
    ag[2][1] = MFMA_BF16(a2, bg1, ag[2][1], 0, 0, 0);
    au[3][0] = MFMA_BF16(a3, bu0, au[3][0], 0, 0, 0);
    au[3][1] = MFMA_BF16(a3, bu1, au[3][1], 0, 0, 0);
    ag[3][0] = MFMA_BF16(a3, bg0, ag[3][0], 0, 0, 0);
    ag[3][1] = MFMA_BF16(a3, bg1, ag[3][1], 0, 0, 0);
    __builtin_amdgcn_s_setprio(0);
    __builtin_amdgcn_sched_barrier(0);
    __builtin_amdgcn_s_barrier();

    // ---------- phase 1: M-half 1, reuse B-frags ----------
    bf16x8 a4 = *(const bf16x8*)&A[abase + 2048 + 0 * 512];
    bf16x8 a5 = *(const bf16x8*)&A[abase + 2048 + 1 * 512];
    bf16x8 a6 = *(const bf16x8*)&A[abase + 2048 + 2 * 512];
    bf16x8 a7 = *(const bf16x8*)&A[abase + 2048 + 3 * 512];
    if (g < 29) ISSUE_B(g + 3);
    // counted vmcnt: require granule g+1 landed; keep g+2/g+3 in flight
    if (g < 29)      asm volatile("s_waitcnt vmcnt(8)" ::: "memory");
    else if (g == 29) asm volatile("s_waitcnt vmcnt(4)" ::: "memory");
    else if (g == 30) asm volatile("s_waitcnt vmcnt(0)" ::: "memory");
    __builtin_amdgcn_sched_barrier(0);
    __builtin_amdgcn_s_barrier();
    asm volatile("s_waitcnt lgkmcnt(0)" ::: "memory");
    __builtin_amdgcn_sched_barrier(0);
    __builtin_amdgcn_s_setprio(1);
    au[4][0] = MFMA_BF16(a4, bu0, au[4][0], 0, 0, 0);
    au[4][1] = MFMA_BF16(a4, bu1, au[4][1], 0, 0, 0);
    ag[4][0] = MFMA_BF16(a4, bg0, ag[4][0], 0, 0, 0);
    ag[4][1] = MFMA_BF16(a4, bg1, ag[4][1], 0, 0, 0);
    au[5][0] = MFMA_BF16(a5, bu0, au[5][0], 0, 0, 0);
    au[5][1] = MFMA_BF16(a5, bu1, au[5][1], 0, 0, 0);
    ag[5][0] = MFMA_BF16(a5, bg0, ag[5][0], 0, 0, 0);
    ag[5][1] = MFMA_BF16(a5, bg1, ag[5][1], 0, 0, 0);
    au[6][0] = MFMA_BF16(a6, bu0, au[6][0], 0, 0, 0);
    au[6][1] = MFMA_BF16(a6, bu1, au[6][1], 0, 0, 0);
    ag[6][0] = MFMA_BF16(a6, bg0, ag[6][0], 0, 0, 0);
    ag[6][1] = MFMA_BF16(a6, bg1, ag[6][1], 0, 0, 0);
    au[7][0] = MFMA_BF16(a7, bu0, au[7][0], 0, 0, 0);
    au[7][1] = MFMA_BF16(a7, bu1, au[7][1], 0, 0, 0);
    ag[7][0] = MFMA_BF16(a7, bg0, ag[7][0], 0, 0, 0);
    ag[7][1] = MFMA_BF16(a7, bg1, ag[7][1], 0, 0, 0);
    __builtin_amdgcn_s_setprio(0);
    __builtin_amdgcn_sched_barrier(0);
    __builtin_amdgcn_s_barrier();
  }

  // epilogue: silu-gate, weight, bf16 store
#pragma unroll
  for (int mi = 0; mi < 8; ++mi) {
#pragma unroll
    for (int reg = 0; reg < 4; ++reg) {
      int lm = (wm << 7) + mi * 16 + q * 4 + reg;
      if (lm < valid) {
        float wrow = wv[r0 + lm];
        size_t orow = (size_t)(r0 + lm) * 2048 + n0 + (wn << 5);
#pragma unroll
        for (int n = 0; n < 2; ++n) {
          float u = au[mi][n][reg];
          float gg = ag[mi][n][reg];
          float s = gg / (1.f + __expf(-gg));
          act[orow + n * 16 + fr] = f2bf(u * s * wrow);
        }
      }
    }
  }
}

// ============================================================================
// GEMM2: out_slot = act @ W2e^T, atomicAdd into out (weight pre-applied).
// Same schedule; tile 128x128, 256 threads (2x2 waves, wave 64x64),
// granule K=32, 4-granule ring = 64 KB -> 2 blocks/CU. NG = 64.
// ============================================================================
__global__ __launch_bounds__(256, 2) void k_gemm2(
    const unsigned short* __restrict__ act,  // [8192][2048] bf16
    const unsigned short* __restrict__ W2b,  // [E][1024][2048] bf16
    const int* __restrict__ meta,
    const int* __restrict__ rows,
    float* __restrict__ out) {               // [4096][1024] fp32
  int bid = blockIdx.x;
  int nt = meta[25];
  int xcd = bid & 7, jj = bid >> 3;
  int y   = jj & 7;
  int tb  = ((jj >> 3) << 3) + xcd;
  if (tb >= nt) return;
  int e     = meta[176 + tb];
  int r0    = meta[248 + tb];
  int valid = meta[320 + tb];
  int n0    = y << 7;

  __shared__ unsigned short lA[4][4096];     // 4 x 8 KB : 128 rows x 32 K
  __shared__ unsigned short lB[4][4096];     // 4 x 8 KB : 128 rows x 32 K

  int tid  = threadIdx.x;
  int wave = tid >> 6, lane = tid & 63;
  int wm = wave >> 1, wn = wave & 1;         // 2 x 2 wave grid
  int fr = lane & 15, q = lane >> 4;
  int swz8 = (q ^ ((fr >> 1) & 3)) << 3;

  const unsigned short* w2e = W2b + (size_t)e * (1024 * 2048);

  const unsigned short *pA[2], *pB[2];
#pragma unroll
  for (int it = 0; it < 2; ++it) {
    int s = it * 256 + tid;                  // 16B slot 0..511
    int r = s >> 2;
    int c = (s & 3) ^ ((s >> 3) & 3);
    pA[it] = act + (size_t)(r0 + MINI(r, valid - 1)) * 2048 + c * 8;
    pB[it] = w2e + (size_t)(n0 + r) * 2048 + c * 8;
  }

  auto ISSUE_A = [&](int g) {
    int sl = g & 3, ko = g * 32;
#pragma unroll
    for (int it = 0; it < 2; ++it)
      GLDS16(pA[it] + ko, &lA[sl][(it * 256 + wave * 64) * 8]);
  };
  auto ISSUE_B = [&](int g) {
    int sl = g & 3, ko = g * 32;
#pragma unroll
    for (int it = 0; it < 2; ++it)
      GLDS16(pB[it] + ko, &lB[sl][(it * 256 + wave * 64) * 8]);
  };

  f32x4 zero = {0.f, 0.f, 0.f, 0.f};
  f32x4 acc[4][4];
#pragma unroll
  for (int i = 0; i < 4; ++i)
#pragma unroll
    for (int n = 0; n < 4; ++n) acc[i][n] = zero;

  int abase = ((wm << 6) + fr) * 32 + swz8;
  int bbase = ((wn << 6) + fr) * 32 + swz8;

  ISSUE_A(0); ISSUE_B(0);
  ISSUE_A(1); ISSUE_B(1);
  ISSUE_A(2); ISSUE_B(2);
  asm volatile("s_waitcnt vmcnt(8)" ::: "memory");
  __builtin_amdgcn_s_barrier();

  for (int g = 0; g < 64; ++g) {
    int sl = g & 3;
    const unsigned short* A = lA[sl];
    const unsigned short* B = lB[sl];

    bf16x8 a0 = *(const bf16x8*)&A[abase + 0 * 512];
    bf16x8 a1 = *(const bf16x8*)&A[abase + 1 * 512];
    bf16x8 a2 = *(const bf16x8*)&A[abase + 2 * 512];
    bf16x8 a3 = *(const bf16x8*)&A[abase + 3 * 512];
    bf16x8 b0 = *(const bf16x8*)&B[bbase + 0 * 512];
    bf16x8 b1 = *(const bf16x8*)&B[bbase + 1 * 512];
    bf16x8 b2 = *(const bf16x8*)&B[bbase + 2 * 512];
    bf16x8 b3 = *(const bf16x8*)&B[bbase + 3 * 512];
    if (g < 61) { ISSUE_A(g + 3); ISSUE_B(g + 3); }
    if (g < 61)      asm volatile("s_waitcnt vmcnt(8)" ::: "memory");
    else if (g == 61) asm volatile("s_waitcnt vmcnt(4)" ::: "memory");
    else if (g == 62) asm volatile("s_waitcnt vmcnt(0)" ::: "memory");
    __builtin_amdgcn_sched_barrier(0);
    __builtin_amdgcn_s_barrier();
    asm volatile("s_waitcnt lgkmcnt(0)" ::: "memory");
    __builtin_amdgcn_sched_barrier(0);
    __builtin_amdgcn_s_setprio(1);
    acc[0][0] = MFMA_BF16(a0, b0, acc[0][0], 0, 0, 0);
    acc[0][1] = MFMA_BF16(a0, b1, acc[0][1], 0, 0, 0);
    acc[0][2] = MFMA_BF16(a0, b2, acc[0][2], 0, 0, 0);
    acc[0][3] = MFMA_BF16(a0, b3, acc[0][3], 0, 0, 0);
    acc[1][0] = MFMA_BF16(a1, b0, acc[1][0], 0, 0, 0);
    acc[1][1] = MFMA_BF16(a1, b1, acc[1][1], 0, 0, 0);
    acc[1][2] = MFMA_BF16(a1, b2, acc[1][2], 0, 0, 0);
    acc[1][3] = MFMA_BF16(a1, b3, acc[1][3], 0, 0, 0);
    acc[2][0] = MFMA_BF16(a2, b0, acc[2][0], 0, 0, 0);
    acc[2][1] = MFMA_BF16(a2, b1, acc[2][1], 0, 0, 0);
    acc[2][2] = MFMA_BF16(a2, b2, acc[2][2], 0, 0, 0);
    acc[2][3] = MFMA_BF16(a2, b3, acc[2][3], 0, 0, 0);
    acc[3][0] = MFMA_BF16(a3, b0, acc[3][0], 0, 0, 0);
    acc[3][1] = MFMA_BF16(a3, b1, acc[3][1], 0, 0, 0);
    acc[3][2] = MFMA_BF16(a3, b2, acc[3][2], 0, 0, 0);
    acc[3][3] = MFMA_BF16(a3, b3, acc[3][3], 0, 0, 0);
    __builtin_amdgcn_s_setprio(0);
    __builtin_amdgcn_sched_barrier(0);
    __builtin_amdgcn_s_barrier();
  }

#pragma unroll
  for (int i = 0; i < 4; ++i) {
#pragma unroll
    for (int reg = 0; reg < 4; ++reg) {
      int lm = (wm << 6) + i * 16 + q * 4 + reg;
      if (lm < valid) {
        int tok = rows[r0 + lm];
        float* op = out + (size_t)tok * 1024 + n0 + (wn << 6);
#pragma unroll
        for (int n = 0; n < 4; ++n)
          atomicAdd(&op[n * 16 + fr], acc[i][n][reg]);
      }
    }
  }
}

extern "C" void kernel_launch(void* const* d_in, const int* in_sizes, int n_in,
                              void* d_out, int out_size, void* d_ws, size_t ws_size,
                              hipStream_t stream) {
  const float* x  = (const float*)d_in[0];   // [T][D]
  const float* w  = (const float*)d_in[1];   // [T][K]
  const int*  idx = (const int*)d_in[2];     // [T][K]
  const float* W1 = (const float*)d_in[3];   // [E][2H][D]
  const float* W2 = (const float*)d_in[4];   // [E][D][H]
  float* out = (float*)d_out;

  char* ws = (char*)d_ws;
  unsigned short* W1b = (unsigned short*)(ws);              // 67108864 B
  unsigned short* W2b = (unsigned short*)(ws + 67108864);   // 33554432 B
  unsigned short* xb  = (unsigned short*)(ws + 100663296);  //  8388608 B
  unsigned short* act = (unsigned short*)(ws + 109051904);  // 33554432 B
  int*   rows = (int*)(ws + 142606336);                     //    32768 B
  float* wv   = (float*)(ws + 142639104);                   //    32768 B
  int*   meta = (int*)(ws + 142671872);                     //     2048 B

  hipMemsetAsync(d_out, 0, (size_t)out_size * sizeof(float), stream);
  hipMemsetAsync(meta, 0, 2048, stream);

  k_cvt8<<<(NCVT8 + 255) / 256, 256, 0, stream>>>(x, W1, W2, xb, W1b, W2b);
  k_route_count<<<32, 256, 0, stream>>>(idx, meta);
  k_route_plan<<<1, 64, 0, stream>>>(meta);
  k_route_scatter<<<32, 256, 0, stream>>>(idx, w, meta, rows, wv);

  k_gemm1<<<MAXT1 * 16, 512, 0, stream>>>(xb, W1b, meta, rows, wv, act);
  k_gemm2<<<MAXT2 * 8, 256, 0, stream>>>(act, W2b, meta, rows, out);
}

// Round 3
// 460.637 us; speedup vs baseline: 1.0748x; 1.0748x over previous
//
#include <hip/hip_runtime.h>
#include <stdint.h>

// Problem constants
#define T_TOK 4096
#define D_DIM 1024
#define H_DIM 2048
#define E_EXP 8
#define K_TOP 2
#define NTK   (T_TOK * K_TOP)   // 8192 (token, slot) pairs
#define MT1 256                 // M-tile rows (both GEMMs)
#define MAXT1 48                // multiple of 8, >= 8192/256 + 8 = 40

typedef short bf16x8 __attribute__((ext_vector_type(8)));
typedef float f32x4  __attribute__((ext_vector_type(4)));

#define MINI(a, b) ((a) < (b) ? (a) : (b))
#define MFMA_BF16 __builtin_amdgcn_mfma_f32_16x16x32_bf16

__device__ __forceinline__ unsigned short f2bf(float f) {
  unsigned u = __float_as_uint(f);
  u += 0x7fffu + ((u >> 16) & 1u);   // round-to-nearest-even
  return (unsigned short)(u >> 16);
}

// async global->LDS, 16B per lane; lds base must be wave-uniform
#define GLDS16(gp, lp)                                                        \
  __builtin_amdgcn_global_load_lds(                                           \
      (const __attribute__((address_space(1))) void*)(gp),                    \
      (__attribute__((address_space(3))) void*)(lp), 16, 0, 0)

// meta layout (ints):
// [0..7] counts, [8..15] offsets, [16..23] scatter cursors, [24] n_tiles
// tiles (M=256): e [32..79], r0 [80..127], valid [128..175]

// ---- routing, parallelized ----

__global__ __launch_bounds__(256) void k_route_count(const int* __restrict__ idx,
                                                     int* __restrict__ meta) {
  __shared__ int h[E_EXP];
  int tid = threadIdx.x;
  if (tid < E_EXP) h[tid] = 0;
  __syncthreads();
  int i = blockIdx.x * 256 + tid;          // 32 blocks x 256 = 8192 exactly
  atomicAdd(&h[idx[i] & (E_EXP - 1)], 1);
  __syncthreads();
  if (tid < E_EXP) atomicAdd(&meta[tid], h[tid]);
}

__global__ __launch_bounds__(64) void k_route_plan(int* __restrict__ meta) {
  if (threadIdx.x) return;
  int off = 0, nt = 0;
  for (int e = 0; e < E_EXP; ++e) {
    int c = meta[e];
    meta[8 + e]  = off;
    meta[16 + e] = off;                     // scatter cursor
    for (int r = 0; r < c; r += MT1) {
      meta[32 + nt]  = e;
      meta[80 + nt]  = off + r;
      meta[128 + nt] = MINI(MT1, c - r);
      ++nt;
    }
    off += c;
  }
  meta[24] = nt;
}

__global__ __launch_bounds__(256) void k_route_scatter(const int* __restrict__ idx,
                                                       const float* __restrict__ w,
                                                       int* __restrict__ meta,
                                                       int* __restrict__ rows,
                                                       float* __restrict__ wv) {
  __shared__ int h[E_EXP], base[E_EXP];
  int tid = threadIdx.x;
  if (tid < E_EXP) h[tid] = 0;
  __syncthreads();
  int i = blockIdx.x * 256 + tid;
  int e = idx[i] & (E_EXP - 1);
  int r = atomicAdd(&h[e], 1);             // block-local rank
  __syncthreads();
  if (tid < E_EXP) base[tid] = atomicAdd(&meta[16 + tid], h[tid]);
  __syncthreads();
  int p = base[e] + r;
  rows[p] = i >> 1;  // K_TOP = 2
  wv[p]   = w[i];
}

// ---- fused f32->bf16 convert, 8 floats/thread, 16B stores ----
#define NX8   (T_TOK * D_DIM / 8)               // 524288
#define NW18  (E_EXP * 2 * H_DIM * D_DIM / 8)   // 4194304
#define NW28  (E_EXP * D_DIM * H_DIM / 8)       // 2097152
#define NCVT8 (NX8 + NW18 + NW28)               // 6815744

__global__ __launch_bounds__(256) void k_cvt8(const float* __restrict__ x,
                                              const float* __restrict__ W1,
                                              const float* __restrict__ W2,
                                              unsigned short* __restrict__ xb,
                                              unsigned short* __restrict__ W1b,
                                              unsigned short* __restrict__ W2b) {
  long gid = (long)blockIdx.x * 256 + threadIdx.x;
  const float* src;
  unsigned short* dst;
  long i;
  if (gid < NX8) {
    src = x; dst = xb; i = gid;
  } else if (gid < NX8 + NW18) {
    src = W1; dst = W1b; i = gid - NX8;
  } else if (gid < NCVT8) {
    src = W2; dst = W2b; i = gid - (NX8 + NW18);
  } else return;
  float4 a = ((const float4*)src)[2 * i];
  float4 b = ((const float4*)src)[2 * i + 1];
  uint4 o;
  o.x = f2bf(a.x) | ((unsigned)f2bf(a.y) << 16);
  o.y = f2bf(a.z) | ((unsigned)f2bf(a.w) << 16);
  o.z = f2bf(b.x) | ((unsigned)f2bf(b.y) << 16);
  o.w = f2bf(b.z) | ((unsigned)f2bf(b.w) << 16);
  ((uint4*)dst)[i] = o;
}

// ============================================================================
// GEMM1: h = Xg @ W1e^T (both strips), act = f2bf(u * silu(gate) * w_row)
// R0-proven structure: 256 threads (4 waves), tile M=256 x 64 act-cols,
// wave tile 64x128, acc 128 regs, LDS 48KB -> 2 blocks/CU (reg-capped).
// Simple 2-barrier K-loop (cross-block TLP does the latency hiding, m114).
// 1-D grid, XCD-grouped: all 32 y-strips of a tile land on one XCD so the
// gathered A-strip (512 KB) is read once into that XCD's L2 and reused 32x.
// ============================================================================
__global__ __launch_bounds__(256, 2) void k_gemm1(
    const unsigned short* __restrict__ xb,   // [T][1024] bf16
    const unsigned short* __restrict__ W1b,  // [E][4096][1024] bf16
    const int* __restrict__ meta,
    const int* __restrict__ rows,
    const float* __restrict__ wv,
    unsigned short* __restrict__ act) {      // [8192][2048] bf16
  int nt = meta[24];
  int bid = blockIdx.x;
  int xcd = bid & 7, jj = bid >> 3;
  int y   = jj & 31;                          // 32 strips of 64 act-cols
  int tb  = ((jj >> 5) << 3) + xcd;
  if (tb >= nt) return;
  int e     = meta[32 + tb];
  int r0    = meta[80 + tb];
  int valid = meta[128 + tb];
  int n0    = y << 6;

  __shared__ unsigned short lA[256 * 64];   // 32 KB
  __shared__ unsigned short lB1[64 * 64];   //  8 KB
  __shared__ unsigned short lB2[64 * 64];   //  8 KB
  __shared__ float sw[256];

  int tid = threadIdx.x;
  int wave = tid >> 6, lane = tid & 63;

  sw[tid] = wv[r0 + MINI(tid, valid - 1)];

  const unsigned short* w1e = W1b + (size_t)e * (4096 * 1024);

  // staging: A = 2048 chunks over 256 threads (8 each), B strips 2 each
  const unsigned short *pA[8], *pB1[2], *pB2[2];
#pragma unroll
  for (int it = 0; it < 8; ++it) {
    int c = it * 256 + tid;
    int r = c >> 3, cc = c & 7;
    int g = cc ^ (r & 7);
    int tok = rows[r0 + MINI(r, valid - 1)];
    pA[it] = xb + (size_t)tok * 1024 + g * 8;
  }
#pragma unroll
  for (int it = 0; it < 2; ++it) {
    int c = it * 256 + tid;
    int r = c >> 3, cc = c & 7;
    int g = cc ^ (r & 7);
    pB1[it] = w1e + (size_t)(n0 + r) * 1024 + g * 8;
    pB2[it] = w1e + (size_t)(2048 + n0 + r) * 1024 + g * 8;
  }

  f32x4 zero = {0.f, 0.f, 0.f, 0.f};
  f32x4 au[4][4], ag[4][4];
#pragma unroll
  for (int i = 0; i < 4; ++i)
#pragma unroll
    for (int j = 0; j < 4; ++j) { au[i][j] = zero; ag[i][j] = zero; }

  int mb = wave * 64;
  int fr = lane & 15, q = lane >> 4;

  for (int k0 = 0; k0 < 1024; k0 += 64) {
    __syncthreads();
#pragma unroll
    for (int it = 0; it < 8; ++it)
      GLDS16(pA[it] + k0, &lA[(it * 256 + wave * 64) * 8]);
#pragma unroll
    for (int it = 0; it < 2; ++it) {
      int lb = (it * 256 + wave * 64) * 8;
      GLDS16(pB1[it] + k0, &lB1[lb]);
      GLDS16(pB2[it] + k0, &lB2[lb]);
    }
    __syncthreads();
#pragma unroll
    for (int kk = 0; kk < 2; ++kk) {
      int co = (((kk << 2) + q) ^ (fr & 7)) * 8 + fr * 64;  // swizzled read
      bf16x8 a[4];
#pragma unroll
      for (int i = 0; i < 4; ++i)
        a[i] = *(const bf16x8*)&lA[(mb + i * 16) * 64 + co];
#pragma unroll
      for (int j = 0; j < 4; ++j) {
        bf16x8 bu = *(const bf16x8*)&lB1[(j * 16) * 64 + co];
        bf16x8 bg = *(const bf16x8*)&lB2[(j * 16) * 64 + co];
#pragma unroll
        for (int i = 0; i < 4; ++i) {
          au[i][j] = MFMA_BF16(a[i], bu, au[i][j], 0, 0, 0);
          ag[i][j] = MFMA_BF16(a[i], bg, ag[i][j], 0, 0, 0);
        }
      }
    }
  }

#pragma unroll
  for (int i = 0; i < 4; ++i) {
#pragma unroll
    for (int reg = 0; reg < 4; ++reg) {
      int lm = mb + i * 16 + q * 4 + reg;
      if (lm < valid) {
        float wrow = sw[lm];
        size_t orow = (size_t)(r0 + lm) * 2048;
#pragma unroll
        for (int j = 0; j < 4; ++j) {
          float u = au[i][j][reg];
          float g = ag[i][j][reg];
          float s = g / (1.f + __expf(-g));
          act[orow + (n0 + j * 16 + fr)] = f2bf(u * s * wrow);
        }
      }
    }
  }
}

// ============================================================================
// GEMM2: out_slot = act @ W2e^T, atomicAdd into d_out (weight pre-applied).
// R0-proven: 256 threads, tile M=256 x N=128, wave 64x128, acc 128 regs,
// LDS 48KB, 2 blocks/CU, simple 2-barrier loop. XCD-grouped 1-D grid
// (8 y-strips of a tile share an XCD -> act A-strip L2 reuse).
// ============================================================================
__global__ __launch_bounds__(256, 2) void k_gemm2(
    const unsigned short* __restrict__ act,  // [8192][2048] bf16
    const unsigned short* __restrict__ W2b,  // [E][1024][2048] bf16
    const int* __restrict__ meta,
    const int* __restrict__ rows,
    float* __restrict__ out) {               // [4096][1024] fp32
  int nt = meta[24];
  int bid = blockIdx.x;
  int xcd = bid & 7, jj = bid >> 3;
  int y   = jj & 7;                           // 8 strips of 128 cols
  int tb  = ((jj >> 3) << 3) + xcd;
  if (tb >= nt) return;
  int e     = meta[32 + tb];
  int r0    = meta[80 + tb];
  int valid = meta[128 + tb];
  int n0    = y << 7;

  __shared__ unsigned short lA[256 * 64];   // 32 KB
  __shared__ unsigned short lB[128 * 64];   // 16 KB
  __shared__ int st[256];

  int tid = threadIdx.x;
  int wave = tid >> 6, lane = tid & 63;
  st[tid] = rows[r0 + MINI(tid, valid - 1)];

  const unsigned short* w2e = W2b + (size_t)e * (1024 * 2048);

  const unsigned short *pA[8], *pB[4];
#pragma unroll
  for (int it = 0; it < 8; ++it) {
    int c = it * 256 + tid;
    int r = c >> 3, cc = c & 7;
    int g = cc ^ (r & 7);
    pA[it] = act + (size_t)(r0 + MINI(r, valid - 1)) * 2048 + g * 8;
  }
#pragma unroll
  for (int it = 0; it < 4; ++it) {
    int c = it * 256 + tid;
    int r = c >> 3, cc = c & 7;
    int g = cc ^ (r & 7);
    pB[it] = w2e + (size_t)(n0 + r) * 2048 + g * 8;
  }

  f32x4 zero = {0.f, 0.f, 0.f, 0.f};
  f32x4 acc[4][8];
#pragma unroll
  for (int i = 0; i < 4; ++i)
#pragma unroll
    for (int j = 0; j < 8; ++j) acc[i][j] = zero;

  int mb = wave * 64;
  int fr = lane & 15, q = lane >> 4;

  for (int k0 = 0; k0 < 2048; k0 += 64) {
    __syncthreads();
#pragma unroll
    for (int it = 0; it < 8; ++it)
      GLDS16(pA[it] + k0, &lA[(it * 256 + wave * 64) * 8]);
#pragma unroll
    for (int it = 0; it < 4; ++it)
      GLDS16(pB[it] + k0, &lB[(it * 256 + wave * 64) * 8]);
    __syncthreads();
#pragma unroll
    for (int kk = 0; kk < 2; ++kk) {
      int co = (((kk << 2) + q) ^ (fr & 7)) * 8 + fr * 64;
      bf16x8 a[4];
#pragma unroll
      for (int i = 0; i < 4; ++i)
        a[i] = *(const bf16x8*)&lA[(mb + i * 16) * 64 + co];
#pragma unroll
      for (int j = 0; j < 8; ++j) {
        bf16x8 b = *(const bf16x8*)&lB[(j * 16) * 64 + co];
#pragma unroll
        for (int i = 0; i < 4; ++i)
          acc[i][j] = MFMA_BF16(a[i], b, acc[i][j], 0, 0, 0);
      }
    }
  }

#pragma unroll
  for (int i = 0; i < 4; ++i) {
#pragma unroll
    for (int reg = 0; reg < 4; ++reg) {
      int lm = mb + i * 16 + q * 4 + reg;
      if (lm < valid) {
        int tok = st[lm];
        float* op = out + (size_t)tok * 1024;
#pragma unroll
        for (int j = 0; j < 8; ++j)
          atomicAdd(&op[n0 + j * 16 + fr], acc[i][j][reg]);
      }
    }
  }
}

extern "C" void kernel_launch(void* const* d_in, const int* in_sizes, int n_in,
                              void* d_out, int out_size, void* d_ws, size_t ws_size,
                              hipStream_t stream) {
  const float* x  = (const float*)d_in[0];   // [T][D]
  const float* w  = (const float*)d_in[1];   // [T][K]
  const int*  idx = (const int*)d_in[2];     // [T][K]
  const float* W1 = (const float*)d_in[3];   // [E][2H][D]
  const float* W2 = (const float*)d_in[4];   // [E][D][H]
  float* out = (float*)d_out;

  char* ws = (char*)d_ws;
  unsigned short* W1b = (unsigned short*)(ws);              // 67108864 B
  unsigned short* W2b = (unsigned short*)(ws + 67108864);   // 33554432 B
  unsigned short* xb  = (unsigned short*)(ws + 100663296);  //  8388608 B
  unsigned short* act = (unsigned short*)(ws + 109051904);  // 33554432 B
  int*   rows = (int*)(ws + 142606336);                     //    32768 B
  float* wv   = (float*)(ws + 142639104);                   //    32768 B
  int*   meta = (int*)(ws + 142671872);                     //     1024 B

  hipMemsetAsync(d_out, 0, (size_t)out_size * sizeof(float), stream);
  hipMemsetAsync(meta, 0, 1024, stream);

  k_cvt8<<<(NCVT8 + 255) / 256, 256, 0, stream>>>(x, W1, W2, xb, W1b, W2b);
  k_route_count<<<32, 256, 0, stream>>>(idx, meta);
  k_route_plan<<<1, 64, 0, stream>>>(meta);
  k_route_scatter<<<32, 256, 0, stream>>>(idx, w, meta, rows, wv);

  k_gemm1<<<MAXT1 * 32, 256, 0, stream>>>(xb, W1b, meta, rows, wv, act);
  k_gemm2<<<MAXT1 * 8, 256, 0, stream>>>(act, W2b, meta, rows, out);
}

// Round 4
// 423.042 us; speedup vs baseline: 1.1703x; 1.0889x over previous
//
#include <hip/hip_runtime.h>
#include <stdint.h>

// Problem constants
#define T_TOK 4096
#define D_DIM 1024
#define H_DIM 2048
#define E_EXP 8
#define K_TOP 2
#define NTK   (T_TOK * K_TOP)   // 8192 (token, slot) pairs
#define MT1 256                 // M-tile rows (both GEMMs)
#define MAXT1 48                // >= 8192/256 + 8 = 40

typedef short bf16x8 __attribute__((ext_vector_type(8)));
typedef float f32x4  __attribute__((ext_vector_type(4)));

#define MINI(a, b) ((a) < (b) ? (a) : (b))
#define MFMA_BF16 __builtin_amdgcn_mfma_f32_16x16x32_bf16

__device__ __forceinline__ unsigned short f2bf(float f) {
  unsigned u = __float_as_uint(f);
  u += 0x7fffu + ((u >> 16) & 1u);   // round-to-nearest-even
  return (unsigned short)(u >> 16);
}

// async global->LDS, 16B per lane; lds base must be wave-uniform
#define GLDS16(gp, lp)                                                        \
  __builtin_amdgcn_global_load_lds(                                           \
      (const __attribute__((address_space(1))) void*)(gp),                    \
      (__attribute__((address_space(3))) void*)(lp), 16, 0, 0)

// meta layout (ints):
// [0..7] counts, [8..15] offsets, [16..23] scatter cursors, [24] n_tiles
// tiles (M=256): e [32..79], r0 [80..127], valid [128..175]

// ---- k_pre: fused cvt(x, W1) + route_count (independent work, one launch) --
#define NX8   (T_TOK * D_DIM / 8)               // 524288
#define NW18  (E_EXP * 2 * H_DIM * D_DIM / 8)   // 4194304
#define NW28  (E_EXP * D_DIM * H_DIM / 8)       // 2097152
#define PRE_CVT_BLKS ((NX8 + NW18) / 256)       // 18432
#define PRE_BLKS (PRE_CVT_BLKS + 32)

__global__ __launch_bounds__(256) void k_pre(const float* __restrict__ x,
                                             const float* __restrict__ W1,
                                             const int* __restrict__ idx,
                                             unsigned short* __restrict__ xb,
                                             unsigned short* __restrict__ W1b,
                                             int* __restrict__ meta) {
  int bid = blockIdx.x;
  int tid = threadIdx.x;
  if (bid >= PRE_CVT_BLKS) {
    // route_count: 32 blocks x 256 = 8192 pairs
    __shared__ int h[E_EXP];
    if (tid < E_EXP) h[tid] = 0;
    __syncthreads();
    int i = (bid - PRE_CVT_BLKS) * 256 + tid;
    atomicAdd(&h[idx[i] & (E_EXP - 1)], 1);
    __syncthreads();
    if (tid < E_EXP) atomicAdd(&meta[tid], h[tid]);
    return;
  }
  long gid = (long)bid * 256 + tid;
  const float* src;
  unsigned short* dst;
  long i;
  if (gid < NX8) { src = x; dst = xb; i = gid; }
  else           { src = W1; dst = W1b; i = gid - NX8; }
  float4 a = ((const float4*)src)[2 * i];
  float4 b = ((const float4*)src)[2 * i + 1];
  uint4 o;
  o.x = f2bf(a.x) | ((unsigned)f2bf(a.y) << 16);
  o.y = f2bf(a.z) | ((unsigned)f2bf(a.w) << 16);
  o.z = f2bf(b.x) | ((unsigned)f2bf(b.y) << 16);
  o.w = f2bf(b.z) | ((unsigned)f2bf(b.w) << 16);
  ((uint4*)dst)[i] = o;
}

__global__ __launch_bounds__(64) void k_route_plan(int* __restrict__ meta) {
  if (threadIdx.x) return;
  int off = 0, nt = 0;
  for (int e = 0; e < E_EXP; ++e) {
    int c = meta[e];
    meta[8 + e]  = off;
    meta[16 + e] = off;                     // scatter cursor
    for (int r = 0; r < c; r += MT1) {
      meta[32 + nt]  = e;
      meta[80 + nt]  = off + r;
      meta[128 + nt] = MINI(MT1, c - r);
      ++nt;
    }
    off += c;
  }
  meta[24] = nt;
}

__global__ __launch_bounds__(256) void k_route_scatter(const int* __restrict__ idx,
                                                       const float* __restrict__ w,
                                                       int* __restrict__ meta,
                                                       int* __restrict__ rows,
                                                       float* __restrict__ wv) {
  __shared__ int h[E_EXP], base[E_EXP];
  int tid = threadIdx.x;
  if (tid < E_EXP) h[tid] = 0;
  __syncthreads();
  int i = blockIdx.x * 256 + tid;
  int e = idx[i] & (E_EXP - 1);
  int r = atomicAdd(&h[e], 1);             // block-local rank
  __syncthreads();
  if (tid < E_EXP) base[tid] = atomicAdd(&meta[16 + tid], h[tid]);
  __syncthreads();
  int p = base[e] + r;
  rows[p] = i >> 1;  // K_TOP = 2
  wv[p]   = w[i];
}

// ============================================================================
// GEMM1 (fat launch): h = Xg @ W1e^T, act = f2bf(u * silu(gate) * w_row)
// Blocks [0, 1536):           R0-proven gemm1 body, R0 2-D dispatch geometry
//                             (tb = bid % 48, y = bid / 48 == x-fastest order).
// Blocks [1536, 1536+1024):   cvt(W2) f32->bf16 (needed only by gemm2) -
//                             hides under gemm1's compute (BW headroom ~4.5TB/s).
// Blocks [2560, 2560+64):     zero d_out for gemm2's atomics.
// ============================================================================
#define G1_TILES (MAXT1 * 32)   // 1536
#define CVW2_BLK 1024
#define ZOUT_BLK 64
#define G1_GRID  (G1_TILES + CVW2_BLK + ZOUT_BLK)

__global__ __launch_bounds__(256, 2) void k_gemm1(
    const unsigned short* __restrict__ xb,   // [T][1024] bf16
    const unsigned short* __restrict__ W1b,  // [E][4096][1024] bf16
    const int* __restrict__ meta,
    const int* __restrict__ rows,
    const float* __restrict__ wv,
    unsigned short* __restrict__ act,        // [8192][2048] bf16
    const float* __restrict__ W2,            // [E][1024][2048] f32
    unsigned short* __restrict__ W2b,        // [E][1024][2048] bf16
    float* __restrict__ out) {               // [4096][1024] f32 (zeroed here)
  int bid = blockIdx.x;
  int tid = threadIdx.x;

  if (bid >= G1_TILES) {
    int xb2 = bid - G1_TILES;
    if (xb2 < CVW2_BLK) {
      // cvt W2: NW28 = 2097152 chunks over 262144 threads -> 8 each
      long g0 = (long)xb2 * 256 + tid;
      for (long i = g0; i < NW28; i += (long)CVW2_BLK * 256) {
        float4 a = ((const float4*)W2)[2 * i];
        float4 b = ((const float4*)W2)[2 * i + 1];
        uint4 o;
        o.x = f2bf(a.x) | ((unsigned)f2bf(a.y) << 16);
        o.y = f2bf(a.z) | ((unsigned)f2bf(a.w) << 16);
        o.z = f2bf(b.x) | ((unsigned)f2bf(b.y) << 16);
        o.w = f2bf(b.z) | ((unsigned)f2bf(b.w) << 16);
        ((uint4*)W2b)[i] = o;
      }
    } else {
      // zero out: 4194304 floats = 262144 uint4 over 16384 threads -> 16 each
      int zb = xb2 - CVW2_BLK;
      long g0 = (long)zb * 256 + tid;
      uint4 z = {0u, 0u, 0u, 0u};
      for (long i = g0; i < (long)(T_TOK * D_DIM / 4); i += (long)ZOUT_BLK * 256)
        ((uint4*)out)[i] = z;
    }
    return;
  }

  int nt = meta[24];
  int tb = bid % MAXT1;                      // R0 geometry: x-fastest
  int y  = bid / MAXT1;
  if (tb >= nt) return;
  int e     = meta[32 + tb];
  int r0    = meta[80 + tb];
  int valid = meta[128 + tb];
  int n0    = y << 6;

  __shared__ unsigned short lA[256 * 64];   // 32 KB
  __shared__ unsigned short lB1[64 * 64];   //  8 KB
  __shared__ unsigned short lB2[64 * 64];   //  8 KB
  __shared__ float sw[256];

  int wave = tid >> 6, lane = tid & 63;

  sw[tid] = wv[r0 + MINI(tid, valid - 1)];

  const unsigned short* w1e = W1b + (size_t)e * (4096 * 1024);

  // staging: A = 2048 chunks over 256 threads (8 each), B strips 2 each
  const unsigned short *pA[8], *pB1[2], *pB2[2];
#pragma unroll
  for (int it = 0; it < 8; ++it) {
    int c = it * 256 + tid;
    int r = c >> 3, cc = c & 7;
    int g = cc ^ (r & 7);
    int tok = rows[r0 + MINI(r, valid - 1)];
    pA[it] = xb + (size_t)tok * 1024 + g * 8;
  }
#pragma unroll
  for (int it = 0; it < 2; ++it) {
    int c = it * 256 + tid;
    int r = c >> 3, cc = c & 7;
    int g = cc ^ (r & 7);
    pB1[it] = w1e + (size_t)(n0 + r) * 1024 + g * 8;
    pB2[it] = w1e + (size_t)(2048 + n0 + r) * 1024 + g * 8;
  }

  f32x4 zero = {0.f, 0.f, 0.f, 0.f};
  f32x4 au[4][4], ag[4][4];
#pragma unroll
  for (int i = 0; i < 4; ++i)
#pragma unroll
    for (int j = 0; j < 4; ++j) { au[i][j] = zero; ag[i][j] = zero; }

  int mb = wave * 64;
  int fr = lane & 15, q = lane >> 4;

  for (int k0 = 0; k0 < 1024; k0 += 64) {
    __syncthreads();
#pragma unroll
    for (int it = 0; it < 8; ++it)
      GLDS16(pA[it] + k0, &lA[(it * 256 + wave * 64) * 8]);
#pragma unroll
    for (int it = 0; it < 2; ++it) {
      int lb = (it * 256 + wave * 64) * 8;
      GLDS16(pB1[it] + k0, &lB1[lb]);
      GLDS16(pB2[it] + k0, &lB2[lb]);
    }
    __syncthreads();
#pragma unroll
    for (int kk = 0; kk < 2; ++kk) {
      int co = (((kk << 2) + q) ^ (fr & 7)) * 8 + fr * 64;  // swizzled read
      bf16x8 a[4];
#pragma unroll
      for (int i = 0; i < 4; ++i)
        a[i] = *(const bf16x8*)&lA[(mb + i * 16) * 64 + co];
#pragma unroll
      for (int j = 0; j < 4; ++j) {
        bf16x8 bu = *(const bf16x8*)&lB1[(j * 16) * 64 + co];
        bf16x8 bg = *(const bf16x8*)&lB2[(j * 16) * 64 + co];
#pragma unroll
        for (int i = 0; i < 4; ++i) {
          au[i][j] = MFMA_BF16(a[i], bu, au[i][j], 0, 0, 0);
          ag[i][j] = MFMA_BF16(a[i], bg, ag[i][j], 0, 0, 0);
        }
      }
    }
  }

#pragma unroll
  for (int i = 0; i < 4; ++i) {
#pragma unroll
    for (int reg = 0; reg < 4; ++reg) {
      int lm = mb + i * 16 + q * 4 + reg;
      if (lm < valid) {
        float wrow = sw[lm];
        size_t orow = (size_t)(r0 + lm) * 2048;
#pragma unroll
        for (int j = 0; j < 4; ++j) {
          float u = au[i][j][reg];
          float g = ag[i][j][reg];
          float s = g / (1.f + __expf(-g));
          act[orow + (n0 + j * 16 + fr)] = f2bf(u * s * wrow);
        }
      }
    }
  }
}

// ============================================================================
// GEMM2: out_slot = act @ W2e^T, atomicAdd into d_out (weight pre-applied).
// R0-proven: 256 threads, tile M=256 x N=128, wave 64x128, acc 128 regs,
// LDS 48KB, 2 blocks/CU, simple 2-barrier loop, R0 2-D grid (48, 8).
// ============================================================================
__global__ __launch_bounds__(256, 2) void k_gemm2(
    const unsigned short* __restrict__ act,  // [8192][2048] bf16
    const unsigned short* __restrict__ W2b,  // [E][1024][2048] bf16
    const int* __restrict__ meta,
    const int* __restrict__ rows,
    float* __restrict__ out) {               // [4096][1024] fp32
  int nt = meta[24];
  int tb = blockIdx.x;
  if (tb >= nt) return;
  int e     = meta[32 + tb];
  int r0    = meta[80 + tb];
  int valid = meta[128 + tb];
  int n0    = blockIdx.y * 128;

  __shared__ unsigned short lA[256 * 64];   // 32 KB
  __shared__ unsigned short lB[128 * 64];   // 16 KB
  __shared__ int st[256];

  int tid = threadIdx.x;
  int wave = tid >> 6, lane = tid & 63;
  st[tid] = rows[r0 + MINI(tid, valid - 1)];

  const unsigned short* w2e = W2b + (size_t)e * (1024 * 2048);

  const unsigned short *pA[8], *pB[4];
#pragma unroll
  for (int it = 0; it < 8; ++it) {
    int c = it * 256 + tid;
    int r = c >> 3, cc = c & 7;
    int g = cc ^ (r & 7);
    pA[it] = act + (size_t)(r0 + MINI(r, valid - 1)) * 2048 + g * 8;
  }
#pragma unroll
  for (int it = 0; it < 4; ++it) {
    int c = it * 256 + tid;
    int r = c >> 3, cc = c & 7;
    int g = cc ^ (r & 7);
    pB[it] = w2e + (size_t)(n0 + r) * 2048 + g * 8;
  }

  f32x4 zero = {0.f, 0.f, 0.f, 0.f};
  f32x4 acc[4][8];
#pragma unroll
  for (int i = 0; i < 4; ++i)
#pragma unroll
    for (int j = 0; j < 8; ++j) acc[i][j] = zero;

  int mb = wave * 64;
  int fr = lane & 15, q = lane >> 4;

  for (int k0 = 0; k0 < 2048; k0 += 64) {
    __syncthreads();
#pragma unroll
    for (int it = 0; it < 8; ++it)
      GLDS16(pA[it] + k0, &lA[(it * 256 + wave * 64) * 8]);
#pragma unroll
    for (int it = 0; it < 4; ++it)
      GLDS16(pB[it] + k0, &lB[(it * 256 + wave * 64) * 8]);
    __syncthreads();
#pragma unroll
    for (int kk = 0; kk < 2; ++kk) {
      int co = (((kk << 2) + q) ^ (fr & 7)) * 8 + fr * 64;
      bf16x8 a[4];
#pragma unroll
      for (int i = 0; i < 4; ++i)
        a[i] = *(const bf16x8*)&lA[(mb + i * 16) * 64 + co];
#pragma unroll
      for (int j = 0; j < 8; ++j) {
        bf16x8 b = *(const bf16x8*)&lB[(j * 16) * 64 + co];
#pragma unroll
        for (int i = 0; i < 4; ++i)
          acc[i][j] = MFMA_BF16(a[i], b, acc[i][j], 0, 0, 0);
      }
    }
  }

#pragma unroll
  for (int i = 0; i < 4; ++i) {
#pragma unroll
    for (int reg = 0; reg < 4; ++reg) {
      int lm = mb + i * 16 + q * 4 + reg;
      if (lm < valid) {
        int tok = st[lm];
        float* op = out + (size_t)tok * 1024;
#pragma unroll
        for (int j = 0; j < 8; ++j)
          atomicAdd(&op[n0 + j * 16 + fr], acc[i][j][reg]);
      }
    }
  }
}

extern "C" void kernel_launch(void* const* d_in, const int* in_sizes, int n_in,
                              void* d_out, int out_size, void* d_ws, size_t ws_size,
                              hipStream_t stream) {
  const float* x  = (const float*)d_in[0];   // [T][D]
  const float* w  = (const float*)d_in[1];   // [T][K]
  const int*  idx = (const int*)d_in[2];     // [T][K]
  const float* W1 = (const float*)d_in[3];   // [E][2H][D]
  const float* W2 = (const float*)d_in[4];   // [E][D][H]
  float* out = (float*)d_out;

  char* ws = (char*)d_ws;
  unsigned short* W1b = (unsigned short*)(ws);              // 67108864 B
  unsigned short* W2b = (unsigned short*)(ws + 67108864);   // 33554432 B
  unsigned short* xb  = (unsigned short*)(ws + 100663296);  //  8388608 B
  unsigned short* act = (unsigned short*)(ws + 109051904);  // 33554432 B
  int*   rows = (int*)(ws + 142606336);                     //    32768 B
  float* wv   = (float*)(ws + 142639104);                   //    32768 B
  int*   meta = (int*)(ws + 142671872);                     //     1024 B

  hipMemsetAsync(meta, 0, 1024, stream);

  k_pre<<<PRE_BLKS, 256, 0, stream>>>(x, W1, idx, xb, W1b, meta);
  k_route_plan<<<1, 64, 0, stream>>>(meta);
  k_route_scatter<<<32, 256, 0, stream>>>(idx, w, meta, rows, wv);

  k_gemm1<<<G1_GRID, 256, 0, stream>>>(xb, W1b, meta, rows, wv, act,
                                       W2, W2b, out);

  dim3 g2(MAXT1, D_DIM / 128);  // (48, 8)
  k_gemm2<<<g2, 256, 0, stream>>>(act, W2b, meta, rows, out);
}

// Round 5
// 407.944 us; speedup vs baseline: 1.2136x; 1.0370x over previous
//
#include <hip/hip_runtime.h>
#include <stdint.h>

// Problem constants
#define T_TOK 4096
#define D_DIM 1024
#define H_DIM 2048
#define E_EXP 8
#define K_TOP 2
#define NTK   (T_TOK * K_TOP)   // 8192 (token, slot) pairs
#define MT1 256                 // M-tile rows (both GEMMs)
#define MAXT1 48                // >= 8192/256 + 8 = 40

typedef short bf16x8 __attribute__((ext_vector_type(8)));
typedef float f32x4  __attribute__((ext_vector_type(4)));

#define MINI(a, b) ((a) < (b) ? (a) : (b))
#define MFMA_BF16 __builtin_amdgcn_mfma_f32_16x16x32_bf16

__device__ __forceinline__ unsigned short f2bf(float f) {
  unsigned u = __float_as_uint(f);
  u += 0x7fffu + ((u >> 16) & 1u);   // round-to-nearest-even
  return (unsigned short)(u >> 16);
}

// async global->LDS, 16B per lane; lds base must be wave-uniform
#define GLDS16(gp, lp)                                                        \
  __builtin_amdgcn_global_load_lds(                                           \
      (const __attribute__((address_space(1))) void*)(gp),                    \
      (__attribute__((address_space(3))) void*)(lp), 16, 0, 0)

// meta layout (ints): [0..7] counts, [16..23] scatter cursors (zero-init)

// Per-block tile lookup from counts (replaces k_route_plan).
__device__ __forceinline__ bool tile_lookup(const int* __restrict__ meta,
                                            int tb, int& e, int& r0, int& valid) {
  int off = 0, acc = 0;
  e = -1; r0 = 0; valid = 0;
#pragma unroll
  for (int ee = 0; ee < E_EXP; ++ee) {
    int c = meta[ee];
    int ntl = (c + MT1 - 1) >> 8;
    int loc = tb - acc;
    if (loc >= 0 && loc < ntl) {
      e = ee; r0 = off + (loc << 8); valid = MINI(MT1, c - (loc << 8));
    }
    acc += ntl; off += c;
  }
  return e >= 0;
}

// ---- k_pre: fused cvt(x, W1) + route_count (independent work, one launch) --
#define NX8   (T_TOK * D_DIM / 8)               // 524288
#define NW18  (E_EXP * 2 * H_DIM * D_DIM / 8)   // 4194304
#define NW28  (E_EXP * D_DIM * H_DIM / 8)       // 2097152
#define PRE_CVT_BLKS ((NX8 + NW18) / 256)       // 18432
#define PRE_BLKS (PRE_CVT_BLKS + 32)

__global__ __launch_bounds__(256) void k_pre(const float* __restrict__ x,
                                             const float* __restrict__ W1,
                                             const int* __restrict__ idx,
                                             unsigned short* __restrict__ xb,
                                             unsigned short* __restrict__ W1b,
                                             int* __restrict__ meta) {
  int bid = blockIdx.x;
  int tid = threadIdx.x;
  if (bid >= PRE_CVT_BLKS) {
    // route_count: 32 blocks x 256 = 8192 pairs
    __shared__ int h[E_EXP];
    if (tid < E_EXP) h[tid] = 0;
    __syncthreads();
    int i = (bid - PRE_CVT_BLKS) * 256 + tid;
    atomicAdd(&h[idx[i] & (E_EXP - 1)], 1);
    __syncthreads();
    if (tid < E_EXP) atomicAdd(&meta[tid], h[tid]);
    return;
  }
  long gid = (long)bid * 256 + tid;
  const float* src;
  unsigned short* dst;
  long i;
  if (gid < NX8) { src = x; dst = xb; i = gid; }
  else           { src = W1; dst = W1b; i = gid - NX8; }
  float4 a = ((const float4*)src)[2 * i];
  float4 b = ((const float4*)src)[2 * i + 1];
  uint4 o;
  o.x = f2bf(a.x) | ((unsigned)f2bf(a.y) << 16);
  o.y = f2bf(a.z) | ((unsigned)f2bf(a.w) << 16);
  o.z = f2bf(b.x) | ((unsigned)f2bf(b.y) << 16);
  o.w = f2bf(b.z) | ((unsigned)f2bf(b.w) << 16);
  ((uint4*)dst)[i] = o;
}

// ---- scatter: offsets computed from counts locally; records slot positions -
__global__ __launch_bounds__(256) void k_route_scatter(const int* __restrict__ idx,
                                                       const float* __restrict__ w,
                                                       int* __restrict__ meta,
                                                       unsigned short* __restrict__ rows,
                                                       unsigned short* __restrict__ slotpos,
                                                       float* __restrict__ wv) {
  __shared__ int h[E_EXP], base[E_EXP];
  int tid = threadIdx.x;
  if (tid < E_EXP) h[tid] = 0;
  __syncthreads();
  int i = blockIdx.x * 256 + tid;
  int e = idx[i] & (E_EXP - 1);
  int r = atomicAdd(&h[e], 1);             // block-local rank
  __syncthreads();
  if (tid < E_EXP) {
    int off = 0;
#pragma unroll
    for (int ee = 0; ee < E_EXP; ++ee)
      if (ee < tid) off += meta[ee];
    base[tid] = off + atomicAdd(&meta[16 + tid], h[tid]);
  }
  __syncthreads();
  int p = base[e] + r;
  rows[p]    = (unsigned short)(i >> 1);   // token (K_TOP = 2)
  slotpos[i] = (unsigned short)p;
  wv[p]      = w[i];
}

// ============================================================================
// GEMM1 (fat launch): h = Xg @ W1e^T, act = f2bf(u * silu(gate) * w_row)
// Blocks [0, 1536):  R0-proven body, R0 2-D geometry (tb = bid%48, y = bid/48)
// Blocks [1536, +1024): cvt(W2) f32->bf16 (only gemm2 needs it) - hides
//                       under gemm1 compute (BW headroom).
// ============================================================================
#define G1_TILES (MAXT1 * 32)   // 1536
#define CVW2_BLK 1024
#define G1_GRID  (G1_TILES + CVW2_BLK)

__global__ __launch_bounds__(256, 2) void k_gemm1(
    const unsigned short* __restrict__ xb,   // [T][1024] bf16
    const unsigned short* __restrict__ W1b,  // [E][4096][1024] bf16
    const int* __restrict__ meta,
    const unsigned short* __restrict__ rows,
    const float* __restrict__ wv,
    unsigned short* __restrict__ act,        // [8192][2048] bf16
    const float* __restrict__ W2,            // [E][1024][2048] f32
    unsigned short* __restrict__ W2b) {      // [E][1024][2048] bf16
  int bid = blockIdx.x;
  int tid = threadIdx.x;

  if (bid >= G1_TILES) {
    // cvt W2: NW28 = 2097152 chunks over 262144 threads -> 8 each
    long g0 = (long)(bid - G1_TILES) * 256 + tid;
    for (long i = g0; i < NW28; i += (long)CVW2_BLK * 256) {
      float4 a = ((const float4*)W2)[2 * i];
      float4 b = ((const float4*)W2)[2 * i + 1];
      uint4 o;
      o.x = f2bf(a.x) | ((unsigned)f2bf(a.y) << 16);
      o.y = f2bf(a.z) | ((unsigned)f2bf(a.w) << 16);
      o.z = f2bf(b.x) | ((unsigned)f2bf(b.y) << 16);
      o.w = f2bf(b.z) | ((unsigned)f2bf(b.w) << 16);
      ((uint4*)W2b)[i] = o;
    }
    return;
  }

  int tb = bid % MAXT1;                      // R0 geometry: x-fastest
  int y  = bid / MAXT1;
  int e, r0, valid;
  if (!tile_lookup(meta, tb, e, r0, valid)) return;
  int n0 = y << 6;

  __shared__ unsigned short lA[256 * 64];   // 32 KB
  __shared__ unsigned short lB1[64 * 64];   //  8 KB
  __shared__ unsigned short lB2[64 * 64];   //  8 KB
  __shared__ float sw[256];

  int wave = tid >> 6, lane = tid & 63;

  sw[tid] = wv[r0 + MINI(tid, valid - 1)];

  const unsigned short* w1e = W1b + (size_t)e * (4096 * 1024);

  // staging: A = 2048 chunks over 256 threads (8 each), B strips 2 each
  const unsigned short *pA[8], *pB1[2], *pB2[2];
#pragma unroll
  for (int it = 0; it < 8; ++it) {
    int c = it * 256 + tid;
    int r = c >> 3, cc = c & 7;
    int g = cc ^ (r & 7);
    int tok = rows[r0 + MINI(r, valid - 1)];
    pA[it] = xb + (size_t)tok * 1024 + g * 8;
  }
#pragma unroll
  for (int it = 0; it < 2; ++it) {
    int c = it * 256 + tid;
    int r = c >> 3, cc = c & 7;
    int g = cc ^ (r & 7);
    pB1[it] = w1e + (size_t)(n0 + r) * 1024 + g * 8;
    pB2[it] = w1e + (size_t)(2048 + n0 + r) * 1024 + g * 8;
  }

  f32x4 zero = {0.f, 0.f, 0.f, 0.f};
  f32x4 au[4][4], ag[4][4];
#pragma unroll
  for (int i = 0; i < 4; ++i)
#pragma unroll
    for (int j = 0; j < 4; ++j) { au[i][j] = zero; ag[i][j] = zero; }

  int mb = wave * 64;
  int fr = lane & 15, q = lane >> 4;

  for (int k0 = 0; k0 < 1024; k0 += 64) {
    __syncthreads();
#pragma unroll
    for (int it = 0; it < 8; ++it)
      GLDS16(pA[it] + k0, &lA[(it * 256 + wave * 64) * 8]);
#pragma unroll
    for (int it = 0; it < 2; ++it) {
      int lb = (it * 256 + wave * 64) * 8;
      GLDS16(pB1[it] + k0, &lB1[lb]);
      GLDS16(pB2[it] + k0, &lB2[lb]);
    }
    __syncthreads();
#pragma unroll
    for (int kk = 0; kk < 2; ++kk) {
      int co = (((kk << 2) + q) ^ (fr & 7)) * 8 + fr * 64;  // swizzled read
      bf16x8 a[4];
#pragma unroll
      for (int i = 0; i < 4; ++i)
        a[i] = *(const bf16x8*)&lA[(mb + i * 16) * 64 + co];
#pragma unroll
      for (int j = 0; j < 4; ++j) {
        bf16x8 bu = *(const bf16x8*)&lB1[(j * 16) * 64 + co];
        bf16x8 bg = *(const bf16x8*)&lB2[(j * 16) * 64 + co];
#pragma unroll
        for (int i = 0; i < 4; ++i) {
          au[i][j] = MFMA_BF16(a[i], bu, au[i][j], 0, 0, 0);
          ag[i][j] = MFMA_BF16(a[i], bg, ag[i][j], 0, 0, 0);
        }
      }
    }
  }

#pragma unroll
  for (int i = 0; i < 4; ++i) {
#pragma unroll
    for (int reg = 0; reg < 4; ++reg) {
      int lm = mb + i * 16 + q * 4 + reg;
      if (lm < valid) {
        float wrow = sw[lm];
        size_t orow = (size_t)(r0 + lm) * 2048;
#pragma unroll
        for (int j = 0; j < 4; ++j) {
          float u = au[i][j][reg];
          float g = ag[i][j][reg];
          float s = g / (1.f + __expf(-g));
          act[orow + (n0 + j * 16 + fr)] = f2bf(u * s * wrow);
        }
      }
    }
  }
}

// ============================================================================
// GEMM2: y_slot = act @ W2e^T (weight pre-applied), PLAIN f32 stores into
// y_slot[8192][1024] (aliased over W1b region, dead after gemm1).
// R0-proven loop: 256 threads, tile M=256 x N=128, wave 64x128, LDS 48KB,
// 2 blocks/CU, simple 2-barrier loop, 2-D grid (48, 8). No atomics.
// ============================================================================
__global__ __launch_bounds__(256, 2) void k_gemm2(
    const unsigned short* __restrict__ act,  // [8192][2048] bf16
    const unsigned short* __restrict__ W2b,  // [E][1024][2048] bf16
    const int* __restrict__ meta,
    float* __restrict__ y) {                 // [8192][1024] fp32 (slot rows)
  int tb = blockIdx.x;
  int e, r0, valid;
  if (!tile_lookup(meta, tb, e, r0, valid)) return;
  int n0 = blockIdx.y * 128;

  __shared__ unsigned short lA[256 * 64];   // 32 KB
  __shared__ unsigned short lB[128 * 64];   // 16 KB

  int tid = threadIdx.x;
  int wave = tid >> 6, lane = tid & 63;

  const unsigned short* w2e = W2b + (size_t)e * (1024 * 2048);

  const unsigned short *pA[8], *pB[4];
#pragma unroll
  for (int it = 0; it < 8; ++it) {
    int c = it * 256 + tid;
    int r = c >> 3, cc = c & 7;
    int g = cc ^ (r & 7);
    pA[it] = act + (size_t)(r0 + MINI(r, valid - 1)) * 2048 + g * 8;
  }
#pragma unroll
  for (int it = 0; it < 4; ++it) {
    int c = it * 256 + tid;
    int r = c >> 3, cc = c & 7;
    int g = cc ^ (r & 7);
    pB[it] = w2e + (size_t)(n0 + r) * 2048 + g * 8;
  }

  f32x4 zero = {0.f, 0.f, 0.f, 0.f};
  f32x4 acc[4][8];
#pragma unroll
  for (int i = 0; i < 4; ++i)
#pragma unroll
    for (int j = 0; j < 8; ++j) acc[i][j] = zero;

  int mb = wave * 64;
  int fr = lane & 15, q = lane >> 4;

  for (int k0 = 0; k0 < 2048; k0 += 64) {
    __syncthreads();
#pragma unroll
    for (int it = 0; it < 8; ++it)
      GLDS16(pA[it] + k0, &lA[(it * 256 + wave * 64) * 8]);
#pragma unroll
    for (int it = 0; it < 4; ++it)
      GLDS16(pB[it] + k0, &lB[(it * 256 + wave * 64) * 8]);
    __syncthreads();
#pragma unroll
    for (int kk = 0; kk < 2; ++kk) {
      int co = (((kk << 2) + q) ^ (fr & 7)) * 8 + fr * 64;
      bf16x8 a[4];
#pragma unroll
      for (int i = 0; i < 4; ++i)
        a[i] = *(const bf16x8*)&lA[(mb + i * 16) * 64 + co];
#pragma unroll
      for (int j = 0; j < 8; ++j) {
        bf16x8 b = *(const bf16x8*)&lB[(j * 16) * 64 + co];
#pragma unroll
        for (int i = 0; i < 4; ++i)
          acc[i][j] = MFMA_BF16(a[i], b, acc[i][j], 0, 0, 0);
      }
    }
  }

#pragma unroll
  for (int i = 0; i < 4; ++i) {
#pragma unroll
    for (int reg = 0; reg < 4; ++reg) {
      int lm = mb + i * 16 + q * 4 + reg;
      if (lm < valid) {
        float* yp = y + (size_t)(r0 + lm) * 1024 + n0;
#pragma unroll
        for (int j = 0; j < 8; ++j)
          yp[j * 16 + fr] = acc[i][j][reg];
      }
    }
  }
}

// ---- combine: out[t] = y[slot0(t)] + y[slot1(t)] (plain streamed adds) ----
__global__ __launch_bounds__(256) void k_combine(
    const float* __restrict__ y,
    const unsigned short* __restrict__ slotpos,
    float* __restrict__ out) {
  int t = blockIdx.x;
  int s0 = slotpos[2 * t], s1 = slotpos[2 * t + 1];
  const float4* a = (const float4*)(y + (size_t)s0 * 1024);
  const float4* b = (const float4*)(y + (size_t)s1 * 1024);
  float4* o = (float4*)(out + (size_t)t * 1024);
  int d = threadIdx.x;                      // 256 x float4 = 1024 floats
  float4 va = a[d], vb = b[d];
  float4 vo = {va.x + vb.x, va.y + vb.y, va.z + vb.z, va.w + vb.w};
  o[d] = vo;
}

extern "C" void kernel_launch(void* const* d_in, const int* in_sizes, int n_in,
                              void* d_out, int out_size, void* d_ws, size_t ws_size,
                              hipStream_t stream) {
  const float* x  = (const float*)d_in[0];   // [T][D]
  const float* w  = (const float*)d_in[1];   // [T][K]
  const int*  idx = (const int*)d_in[2];     // [T][K]
  const float* W1 = (const float*)d_in[3];   // [E][2H][D]
  const float* W2 = (const float*)d_in[4];   // [E][D][H]
  float* out = (float*)d_out;

  char* ws = (char*)d_ws;
  unsigned short* W1b = (unsigned short*)(ws);              // 67108864 B
  float*          yslot = (float*)(ws);                     // 33554432 B (alias, after gemm1)
  unsigned short* W2b = (unsigned short*)(ws + 67108864);   // 33554432 B
  unsigned short* xb  = (unsigned short*)(ws + 100663296);  //  8388608 B
  unsigned short* act = (unsigned short*)(ws + 109051904);  // 33554432 B
  unsigned short* rows    = (unsigned short*)(ws + 142606336);  // 16384 B
  unsigned short* slotpos = (unsigned short*)(ws + 142622720);  // 16384 B
  float* wv   = (float*)(ws + 142639104);                   //    32768 B
  int*   meta = (int*)(ws + 142671872);                     //     1024 B

  hipMemsetAsync(meta, 0, 1024, stream);

  k_pre<<<PRE_BLKS, 256, 0, stream>>>(x, W1, idx, xb, W1b, meta);
  k_route_scatter<<<32, 256, 0, stream>>>(idx, w, meta, rows, slotpos, wv);

  k_gemm1<<<G1_GRID, 256, 0, stream>>>(xb, W1b, meta, rows, wv, act, W2, W2b);

  dim3 g2(MAXT1, D_DIM / 128);  // (48, 8)
  k_gemm2<<<g2, 256, 0, stream>>>(act, W2b, meta, yslot);

  k_combine<<<T_TOK, 256, 0, stream>>>(yslot, slotpos, out);
}